// Round 1
// baseline (316.263 us; speedup 1.0000x reference)
//
#include <hip/hip_runtime.h>

// TriDiagonalLaplaceSolver: B=4096 independent rows, N=8192 per row.
// Thomas algorithm with precomputed LU factors a (N), b (N-1), c (N-1).
//   fwd: y[i] = x[i] - c[i-1]*y[i-1]        (y[0] = x[0])
//   bwd: z[i] = (y[i] - b[i]*z[i+1])/a[i]   (z[N-1] = y[N-1]/a[N-1])
// Both recurrences contract with ratio ~0.268/step, so a halo of HALO=32
// zero-initialized warm-up steps reproduces exact state to ~5e-19 relative.
// => chunk rows into CHUNK=128 segments, keep y window in registers,
//    single pass, compulsory-ish traffic: 1.5x read + 1x write = 320 MiB.

#define NN    8192
#define BB    4096
#define CHUNK 128
#define HALO  32
#define WIN   (CHUNK + HALO)   // stored y values per thread (registers)

__device__ __forceinline__ float fast_rcp(float v) {
#if defined(__has_builtin) && __has_builtin(__builtin_amdgcn_rcpf)
    float r = __builtin_amdgcn_rcpf(v);
    r = r * (2.0f - v * r);   // one NR step -> ~0.5 ulp
    return r;
#else
    return 1.0f / v;
#endif
}

template<bool FIRST, bool EDGE>
__device__ __forceinline__ void solve_window(
    const float* __restrict__ xrow,
    const float* __restrict__ a,
    const float* __restrict__ b,
    const float* __restrict__ c,
    float* __restrict__ orow,
    int s)
{
    const float* xs = xrow + s;
    const float* as = a + s;
    const float* bs = b + s;
    const float* cs = c + s;   // c[i-1] == cs[k-1]

    float y = 0.0f;

    if (!FIRST) {
        // forward warm-up over [s-HALO, s): contraction kills the zero-init error
        const float* xw = xrow + (s - HALO);
        const float* cw = c + (s - HALO);
        #pragma unroll
        for (int k = 0; k < HALO; k += 4) {
            float4 xv = *(const float4*)(xw + k);
            y = xv.x - cw[k - 1] * y;
            y = xv.y - cw[k]     * y;
            y = xv.z - cw[k + 1] * y;
            y = xv.w - cw[k + 2] * y;
        }
    }

    // forward main: store y for [s, s+WIN)  (EDGE: only [s, s+CHUNK), ends at N)
    float ybuf[WIN];
    #pragma unroll
    for (int k = 0; k < (EDGE ? CHUNK : WIN); k += 4) {
        float4 xv = *(const float4*)(xs + k);
        float c0 = (FIRST && k == 0) ? 0.0f : cs[k - 1];
        y = xv.x - c0        * y;  ybuf[k]     = y;
        y = xv.y - cs[k]     * y;  ybuf[k + 1] = y;
        y = xv.z - cs[k + 1] * y;  ybuf[k + 2] = y;
        y = xv.w - cs[k + 2] * y;  ybuf[k + 3] = y;
    }

    float z = 0.0f;
    if (!EDGE) {
        // backward warm-up over [s+CHUNK, s+WIN)
        #pragma unroll
        for (int k = WIN - 1; k >= CHUNK; --k) {
            z = (ybuf[k] - bs[k] * z) * fast_rcp(as[k]);
        }
        #pragma unroll
        for (int kg = CHUNK - 4; kg >= 0; kg -= 4) {
            float4 zv;
            z = (ybuf[kg + 3] - bs[kg + 3] * z) * fast_rcp(as[kg + 3]); zv.w = z;
            z = (ybuf[kg + 2] - bs[kg + 2] * z) * fast_rcp(as[kg + 2]); zv.z = z;
            z = (ybuf[kg + 1] - bs[kg + 1] * z) * fast_rcp(as[kg + 1]); zv.y = z;
            z = (ybuf[kg]     - bs[kg]     * z) * fast_rcp(as[kg]);     zv.x = z;
            *(float4*)(orow + s + kg) = zv;
        }
    } else {
        // last chunk: z[N-1] = y[N-1]/a[N-1]  (b_pad[N-1] = 0, z starts at 0)
        {
            float4 zv;
            z = ybuf[CHUNK - 1] * fast_rcp(as[CHUNK - 1]);                          zv.w = z;
            z = (ybuf[CHUNK - 2] - bs[CHUNK - 2] * z) * fast_rcp(as[CHUNK - 2]);    zv.z = z;
            z = (ybuf[CHUNK - 3] - bs[CHUNK - 3] * z) * fast_rcp(as[CHUNK - 3]);    zv.y = z;
            z = (ybuf[CHUNK - 4] - bs[CHUNK - 4] * z) * fast_rcp(as[CHUNK - 4]);    zv.x = z;
            *(float4*)(orow + s + CHUNK - 4) = zv;
        }
        #pragma unroll
        for (int kg = CHUNK - 8; kg >= 0; kg -= 4) {
            float4 zv;
            z = (ybuf[kg + 3] - bs[kg + 3] * z) * fast_rcp(as[kg + 3]); zv.w = z;
            z = (ybuf[kg + 2] - bs[kg + 2] * z) * fast_rcp(as[kg + 2]); zv.z = z;
            z = (ybuf[kg + 1] - bs[kg + 1] * z) * fast_rcp(as[kg + 1]); zv.y = z;
            z = (ybuf[kg]     - bs[kg]     * z) * fast_rcp(as[kg]);     zv.x = z;
            *(float4*)(orow + s + kg) = zv;
        }
    }
}

__global__ __launch_bounds__(256, 2) void TriDiagonalLaplaceSolver_kernel(
    const float* __restrict__ x,
    const float* __restrict__ a,
    const float* __restrict__ b,
    const float* __restrict__ c,
    float* __restrict__ out)
{
    const int chunk = blockIdx.x;                    // 0 .. NN/CHUNK-1
    const int row   = blockIdx.y * 256 + threadIdx.x;
    const int s     = chunk * CHUNK;

    const float* xrow = x   + (size_t)row * NN;
    float*       orow = out + (size_t)row * NN;

    if (chunk == 0) {
        solve_window<true, false>(xrow, a, b, c, orow, 0);
    } else if (chunk == (NN / CHUNK) - 1) {
        solve_window<false, true>(xrow, a, b, c, orow, s);
    } else {
        solve_window<false, false>(xrow, a, b, c, orow, s);
    }
}

extern "C" void kernel_launch(void* const* d_in, const int* in_sizes, int n_in,
                              void* d_out, int out_size, void* d_ws, size_t ws_size,
                              hipStream_t stream) {
    const float* x = (const float*)d_in[0];
    const float* a = (const float*)d_in[1];
    const float* b = (const float*)d_in[2];
    const float* c = (const float*)d_in[3];
    float* out = (float*)d_out;

    dim3 grid(NN / CHUNK, BB / 256);   // 64 chunks x 16 row-groups = 1024 blocks
    dim3 block(256);
    TriDiagonalLaplaceSolver_kernel<<<grid, block, 0, stream>>>(x, a, b, c, out);
}